// Round 3
// baseline (298.920 us; speedup 1.0000x reference)
//
#include <hip/hip_runtime.h>
#include <hip/hip_bf16.h>

typedef __attribute__((ext_vector_type(8))) short short8;
typedef __attribute__((ext_vector_type(4))) float f32x4;
typedef __attribute__((ext_vector_type(4))) unsigned int u32x4;
typedef __attribute__((ext_vector_type(2))) unsigned int u32x2;

#define DIN  4096
#define DOUT 4096
#define NTOK 16384

static __device__ __forceinline__ unsigned short f2b(float f) {
  union { __hip_bfloat16 h; unsigned short u; } cv;
  cv.h = __float2bfloat16(f);
  return cv.u;
}

static __device__ __forceinline__ short8 pack8(float4 f0, float4 f1) {
  short8 s;
  s[0] = (short)f2b(f0.x); s[1] = (short)f2b(f0.y);
  s[2] = (short)f2b(f0.z); s[3] = (short)f2b(f0.w);
  s[4] = (short)f2b(f1.x); s[5] = (short)f2b(f1.y);
  s[6] = (short)f2b(f1.z); s[7] = (short)f2b(f1.w);
  return s;
}

// ------------- prologue (merged): transpose+convert weights to bf16 ----------
// btt_r[n][b][k] f32 -> Rt[n][c=k][b] bf16 ; btt_l[m][j][a] f32 -> Lt[m][a][j]
__global__ __launch_bounds__(256) void prep(const float* __restrict__ r,
                                            const float* __restrict__ l,
                                            unsigned short* __restrict__ rt,
                                            unsigned short* __restrict__ lt) {
  __shared__ unsigned short tile[128 * 68];
  const int q = threadIdx.x;
  if (blockIdx.x < 64) {
    const int n = blockIdx.x;
#pragma unroll
    for (int it = 0; it < 8; ++it) {
      const int idx = q + it * 256;           // float4 units
      const int b = idx >> 5, k4 = idx & 31;
      const float4 v = *(const float4*)(r + (size_t)n * 8192 + b * 128 + k4 * 4);
      unsigned int lo = (unsigned)f2b(v.x) | ((unsigned)f2b(v.y) << 16);
      unsigned int hi = (unsigned)f2b(v.z) | ((unsigned)f2b(v.w) << 16);
      u32x2 pk = {lo, hi};
      *(u32x2*)((char*)tile + (b * 264 + k4 * 8)) = pk;   // [b][k] stride 132
    }
    __syncthreads();
#pragma unroll
    for (int it = 0; it < 32; ++it) {
      const int o = q + it * 256;             // o = c*64 + b
      const int c = o >> 6, b = o & 63;
      rt[(size_t)n * 8192 + o] = tile[b * 132 + c];
    }
  } else {
    const int m = blockIdx.x - 64;
#pragma unroll
    for (int it = 0; it < 8; ++it) {
      const int idx = q + it * 256;
      const int j = idx >> 4, a4 = idx & 15;
      const float4 v = *(const float4*)(l + (size_t)m * 8192 + j * 64 + a4 * 4);
      unsigned int lo = (unsigned)f2b(v.x) | ((unsigned)f2b(v.y) << 16);
      unsigned int hi = (unsigned)f2b(v.z) | ((unsigned)f2b(v.w) << 16);
      u32x2 pk = {lo, hi};
      *(u32x2*)((char*)tile + (j * 136 + a4 * 8)) = pk;   // [j][a] stride 68
    }
    __syncthreads();
#pragma unroll
    for (int it = 0; it < 32; ++it) {
      const int o = q + it * 256;             // o = a*128 + j
      const int a = o >> 7, j = o & 127;
      lt[(size_t)m * 8192 + o] = tile[j * 68 + a];
    }
  }
}

// ---------------- kernel1: stage1, barrier-free streaming --------------------
// h layout (chunk-local): [tile16][n][c][t&15] bf16
// grid: (strips, 64 n); block 256 = 4 waves; wave = one 16-token tile x all c
__global__ __launch_bounds__(256) void k1(const float* __restrict__ x,
                                          const unsigned short* __restrict__ rt,
                                          unsigned short* __restrict__ hbuf,
                                          int tok0) {
  const int n = blockIdx.y;
  const int strip = blockIdx.x;
  const int wave = threadIdx.x >> 6, lane = threadIdx.x & 63;
  const int l15 = lane & 15, l4 = lane >> 4;

  // B-fragments register-resident: Rt[n][c=ct*16+l15][b=ks*32+l4*8 ..+8]
  short8 bf[8][2];
  {
    const unsigned short* rbase = rt + (size_t)n * 8192 + l15 * 64 + l4 * 8;
#pragma unroll
    for (int ct = 0; ct < 8; ++ct)
#pragma unroll
      for (int ks = 0; ks < 2; ++ks)
        bf[ct][ks] = *(const short8*)(rbase + ct * 1024 + ks * 32);
  }

  for (int tt = 0; tt < 4; ++tt) {
    const int tile = strip * 16 + tt * 4 + wave;      // chunk-local 16-tok tile
    const float* xr = x + (size_t)(tok0 + tile * 16 + l15) * DIN + n * 64 + l4 * 8;
    const float4 f0 = *(const float4*)(xr);
    const float4 f1 = *(const float4*)(xr + 4);
    const float4 g0 = *(const float4*)(xr + 32);
    const float4 g1 = *(const float4*)(xr + 36);
    const short8 a0 = pack8(f0, f1);
    const short8 a1 = pack8(g0, g1);
    unsigned short* hb = hbuf + (size_t)(tile * 64 + n) * 2048 + l15 * 16 + l4 * 4;
#pragma unroll
    for (int ct = 0; ct < 8; ++ct) {
      f32x4 acc = {0.f, 0.f, 0.f, 0.f};
      acc = __builtin_amdgcn_mfma_f32_16x16x32_bf16(a0, bf[ct][0], acc, 0, 0, 0);
      acc = __builtin_amdgcn_mfma_f32_16x16x32_bf16(a1, bf[ct][1], acc, 0, 0, 0);
      unsigned int lo = (unsigned)f2b(acc[0]) | ((unsigned)f2b(acc[1]) << 16);
      unsigned int hi = (unsigned)f2b(acc[2]) | ((unsigned)f2b(acc[3]) << 16);
      u32x2 pk = {lo, hi};
      *(u32x2*)(hb + ct * 256) = pk;                  // 512B contiguous per wave
    }
  }
}

// ---------------- kernel2: stage2, Lt in registers, dbuf A-transpose ---------
// grid: (strips, 64 m); block 256 = 4 waves; wave = one a-tile (16 a) x 32 tok
__global__ __launch_bounds__(256) void k2(const unsigned short* __restrict__ hbuf,
                                          const unsigned short* __restrict__ lt,
                                          const float* __restrict__ bias,
                                          float* __restrict__ y,
                                          int tok0) {
  __shared__ unsigned short as_[2][32 * 128];
  const int m = blockIdx.y;
  const int strip = blockIdx.x;
  const int tid = threadIdx.x;
  const int wave = tid >> 6, lane = tid & 63;
  const int l15 = lane & 15, l4 = lane >> 4;

  // B-fragments: Lt[m][a=wave*16+l15][j=ks*32+l4*8 ..+8]
  short8 bfr[4];
  {
    const unsigned short* lbase = lt + (size_t)m * 8192 + (wave * 16 + l15) * 128 + l4 * 8;
#pragma unroll
    for (int ks = 0; ks < 4; ++ks) bfr[ks] = *(const short8*)(lbase + ks * 32);
  }
  const int acol = wave * 16 + l15;
  const float bv = bias[m * 64 + acol];

  auto stage = [&](int it, int b) {
#pragma unroll
    for (int half = 0; half < 2; ++half) {
      const int idx = tid + half * 256;
      const int hh = idx & 1, nr = (idx >> 1) & 127, tio = idx >> 8;
      const int nn = nr >> 1, r2 = nr & 1;
      const int tg16 = strip * 16 + it * 2 + tio;
      const u32x4 v = *(const u32x4*)(hbuf + (size_t)(tg16 * 64 + nn) * 2048 +
                                      (m * 2 + r2) * 16 + hh * 8);
#pragma unroll
      for (int e = 0; e < 8; ++e) {
        const unsigned int w = v[e >> 1];
        const unsigned short val = (e & 1) ? (unsigned short)(w >> 16)
                                           : (unsigned short)(w & 0xffff);
        const int t = tio * 16 + hh * 8 + e;
        *(unsigned short*)((char*)as_[b] + (t * 256 + ((nr * 2) ^ ((t & 7) << 4)))) = val;
      }
    }
  };

  stage(0, 0);
  __syncthreads();
  int buf = 0;
  for (int it = 0; it < 8; ++it) {
    if (it + 1 < 8) stage(it + 1, buf ^ 1);
#pragma unroll
    for (int th = 0; th < 2; ++th) {
      const int ta = th * 16 + l15;
      f32x4 acc = {0.f, 0.f, 0.f, 0.f};
#pragma unroll
      for (int ks = 0; ks < 4; ++ks) {
        const short8 av = *(const short8*)((char*)as_[buf] +
                            (ta * 256 + ((ks * 64 + l4 * 16) ^ ((ta & 7) << 4))));
        acc = __builtin_amdgcn_mfma_f32_16x16x32_bf16(av, bfr[ks], acc, 0, 0, 0);
      }
      const size_t t0 = (size_t)(tok0 + strip * 256 + it * 32 + th * 16 + l4 * 4);
#pragma unroll
      for (int jj = 0; jj < 4; ++jj)
        y[(t0 + jj) * DOUT + m * 64 + acol] = acc[jj] + bv;
    }
    __syncthreads();
    buf ^= 1;
  }
}

extern "C" void kernel_launch(void* const* d_in, const int* in_sizes, int n_in,
                              void* d_out, int out_size, void* d_ws, size_t ws_size,
                              hipStream_t stream) {
  const float* x    = (const float*)d_in[0];
  const float* bl   = (const float*)d_in[1];
  const float* br   = (const float*)d_in[2];
  const float* bias = (const float*)d_in[3];
  float* y = (float*)d_out;

  unsigned short* rt   = (unsigned short*)d_ws;          // 1 MB
  unsigned short* ltw  = rt + 64 * 8192;                 // 1 MB
  unsigned short* hbuf = ltw + 64 * 8192;                // chunk*8192*2 B

  const size_t fixed = (size_t)2 * 64 * 8192 * 2;
  int chunk = 4096;                                      // h chunk L3-resident
  while (chunk > 256 && fixed + (size_t)chunk * 8192 * 2 > ws_size) chunk >>= 1;
  const int nchunk = NTOK / chunk;
  const int strips = chunk / 256;                        // 256 tokens per strip

  prep<<<128, 256, 0, stream>>>(br, bl, rt, ltw);
  for (int c = 0; c < nchunk; ++c) {
    k1<<<dim3(strips, 64), 256, 0, stream>>>(x, rt, hbuf, c * chunk);
    k2<<<dim3(strips, 64), 256, 0, stream>>>(hbuf, ltw, bias, y, c * chunk);
  }
}

// Round 4
// 293.158 us; speedup vs baseline: 1.0197x; 1.0197x over previous
//
#include <hip/hip_runtime.h>
#include <hip/hip_bf16.h>

typedef __attribute__((ext_vector_type(8))) short short8;
typedef __attribute__((ext_vector_type(4))) float f32x4;
typedef __attribute__((ext_vector_type(4))) unsigned int u32x4;
typedef __attribute__((ext_vector_type(2))) unsigned int u32x2;

#define DIN  4096
#define DOUT 4096
#define NTOK 16384

static __device__ __forceinline__ unsigned short f2b(float f) {
  union { __hip_bfloat16 h; unsigned short u; } cv;
  cv.h = __float2bfloat16(f);
  return cv.u;
}

static __device__ __forceinline__ short8 pack8(float4 f0, float4 f1) {
  short8 s;
  s[0] = (short)f2b(f0.x); s[1] = (short)f2b(f0.y);
  s[2] = (short)f2b(f0.z); s[3] = (short)f2b(f0.w);
  s[4] = (short)f2b(f1.x); s[5] = (short)f2b(f1.y);
  s[6] = (short)f2b(f1.z); s[7] = (short)f2b(f1.w);
  return s;
}

// ------------- prologue (merged): transpose+convert weights to bf16 ----------
// btt_r[n][b][k] f32 -> Rt[n][c=k][b] bf16 ; btt_l[m][j][a] f32 -> Lt[m][a][j]
__global__ __launch_bounds__(256) void prep(const float* __restrict__ r,
                                            const float* __restrict__ l,
                                            unsigned short* __restrict__ rt,
                                            unsigned short* __restrict__ lt) {
  __shared__ unsigned short tile[128 * 68];
  const int q = threadIdx.x;
  if (blockIdx.x < 64) {
    const int n = blockIdx.x;
#pragma unroll
    for (int it = 0; it < 8; ++it) {
      const int idx = q + it * 256;           // float4 units
      const int b = idx >> 5, k4 = idx & 31;
      const float4 v = *(const float4*)(r + (size_t)n * 8192 + b * 128 + k4 * 4);
      unsigned int lo = (unsigned)f2b(v.x) | ((unsigned)f2b(v.y) << 16);
      unsigned int hi = (unsigned)f2b(v.z) | ((unsigned)f2b(v.w) << 16);
      u32x2 pk = {lo, hi};
      *(u32x2*)((char*)tile + (b * 264 + k4 * 8)) = pk;   // [b][k] stride 132
    }
    __syncthreads();
#pragma unroll
    for (int it = 0; it < 32; ++it) {
      const int o = q + it * 256;             // o = c*64 + b
      const int c = o >> 6, b = o & 63;
      rt[(size_t)n * 8192 + o] = tile[b * 132 + c];
    }
  } else {
    const int m = blockIdx.x - 64;
#pragma unroll
    for (int it = 0; it < 8; ++it) {
      const int idx = q + it * 256;
      const int j = idx >> 4, a4 = idx & 15;
      const float4 v = *(const float4*)(l + (size_t)m * 8192 + j * 64 + a4 * 4);
      unsigned int lo = (unsigned)f2b(v.x) | ((unsigned)f2b(v.y) << 16);
      unsigned int hi = (unsigned)f2b(v.z) | ((unsigned)f2b(v.w) << 16);
      u32x2 pk = {lo, hi};
      *(u32x2*)((char*)tile + (j * 136 + a4 * 8)) = pk;   // [j][a] stride 68
    }
    __syncthreads();
#pragma unroll
    for (int it = 0; it < 32; ++it) {
      const int o = q + it * 256;             // o = a*128 + j
      const int a = o >> 7, j = o & 127;
      lt[(size_t)m * 8192 + o] = tile[j * 68 + a];
    }
  }
}

// ---------------- kernel1: stage1, barrier-free streaming, prefetched --------
// h layout (chunk-local): [tile16][n][c][t&15] bf16
// grid: (chunk/256, 64 n); block 256 = 4 waves; wave = 4 16-token tiles x all c
__global__ __launch_bounds__(256) void k1(const float* __restrict__ x,
                                          const unsigned short* __restrict__ rt,
                                          unsigned short* __restrict__ hbuf,
                                          int tok0) {
  const int n = blockIdx.y;
  const int strip = blockIdx.x;
  const int wave = threadIdx.x >> 6, lane = threadIdx.x & 63;
  const int l15 = lane & 15, l4 = lane >> 4;

  // B-fragments register-resident: Rt[n][c=ct*16+l15][b=ks*32+l4*8 ..+8]
  short8 bf[8][2];
  {
    const unsigned short* rbase = rt + (size_t)n * 8192 + l15 * 64 + l4 * 8;
#pragma unroll
    for (int ct = 0; ct < 8; ++ct)
#pragma unroll
      for (int ks = 0; ks < 2; ++ks)
        bf[ct][ks] = *(const short8*)(rbase + ct * 1024 + ks * 32);
  }

  const float* xb = x + (size_t)(tok0 + (strip * 16 + wave) * 16 + l15) * DIN
                      + n * 64 + l4 * 8;
  // static 2-buffer prefetch (fully unrolled -> register resident)
  float4 p0[4], p1[4];
  p0[0] = *(const float4*)(xb);      p0[1] = *(const float4*)(xb + 4);
  p0[2] = *(const float4*)(xb + 32); p0[3] = *(const float4*)(xb + 36);
#pragma unroll
  for (int tt = 0; tt < 4; ++tt) {
    if (tt < 3) {
      const float* xn = xb + (size_t)(tt + 1) * 4 * 16 * DIN;
      float4* dst = (tt & 1) ? p0 : p1;
      dst[0] = *(const float4*)(xn);      dst[1] = *(const float4*)(xn + 4);
      dst[2] = *(const float4*)(xn + 32); dst[3] = *(const float4*)(xn + 36);
    }
    const float4* cur = (tt & 1) ? p1 : p0;
    const short8 a0 = pack8(cur[0], cur[1]);
    const short8 a1 = pack8(cur[2], cur[3]);
    const int tile = strip * 16 + tt * 4 + wave;
    unsigned short* hb = hbuf + (size_t)(tile * 64 + n) * 2048 + l15 * 16 + l4 * 4;
#pragma unroll
    for (int ct = 0; ct < 8; ++ct) {
      f32x4 acc = {0.f, 0.f, 0.f, 0.f};
      acc = __builtin_amdgcn_mfma_f32_16x16x32_bf16(a0, bf[ct][0], acc, 0, 0, 0);
      acc = __builtin_amdgcn_mfma_f32_16x16x32_bf16(a1, bf[ct][1], acc, 0, 0, 0);
      unsigned int lo = (unsigned)f2b(acc[0]) | ((unsigned)f2b(acc[1]) << 16);
      unsigned int hi = (unsigned)f2b(acc[2]) | ((unsigned)f2b(acc[3]) << 16);
      u32x2 pk = {lo, hi};
      *(u32x2*)(hb + ct * 256) = pk;                  // 512B contiguous per wave
    }
  }
}

// ---------------- kernel2: stage2, m-paired (full-line hbuf reads) -----------
// block owns m-pair mp -> c in {4mp..4mp+3} = 128B contiguous per (tile,n)
// grid: (chunk/128, 32 mp); block 256 = 4 waves: wave = (m_loc, a-half)
__global__ __launch_bounds__(256) void k2(const unsigned short* __restrict__ hbuf,
                                          const unsigned short* __restrict__ lt,
                                          const float* __restrict__ bias,
                                          float* __restrict__ y,
                                          int tok0) {
  __shared__ unsigned short as_[2][2][32 * 128];  // [buf][m_loc][t][j] swizzled
  const int mp = blockIdx.y;
  const int strip = blockIdx.x;
  const int tid = threadIdx.x;
  const int wave = tid >> 6, lane = tid & 63;
  const int l15 = lane & 15, l4 = lane >> 4;
  const int m_loc = wave & 1, ah = wave >> 1;
  const int m = mp * 2 + m_loc;

  // B-fragments: Lt[m][a][j=ks*32+l4*8..+8], a = ah*32 + at*16 + l15
  short8 bfr[2][4];
#pragma unroll
  for (int at = 0; at < 2; ++at)
#pragma unroll
    for (int ks = 0; ks < 4; ++ks)
      bfr[at][ks] = *(const short8*)(lt + (size_t)m * 8192 +
                      (ah * 32 + at * 16 + l15) * 128 + ks * 32 + l4 * 8);
  const float bv0 = bias[m * 64 + ah * 32 + l15];
  const float bv1 = bias[m * 64 + ah * 32 + 16 + l15];

  auto stage = [&](int it, int b) {
#pragma unroll
    for (int half = 0; half < 4; ++half) {
      const int idx = tid + half * 256;           // 0..1023 16B units
      const int sub8 = idx & 7, nn = (idx >> 3) & 63, tio = idx >> 9;
      const int tg16 = strip * 8 + it * 2 + tio;
      const u32x4 v = *(const u32x4*)(hbuf + (size_t)(tg16 * 64 + nn) * 2048 +
                                      mp * 64 + sub8 * 8);
      const int c_loc = sub8 >> 1, hh = sub8 & 1;
      const int j = nn * 2 + (c_loc & 1), ml = c_loc >> 1;
      char* base = (char*)as_ + ((b * 2 + ml) * 32) * 256;
#pragma unroll
      for (int e = 0; e < 8; ++e) {
        const unsigned int w = v[e >> 1];
        const unsigned short val = (e & 1) ? (unsigned short)(w >> 16)
                                           : (unsigned short)(w & 0xffff);
        const int t = tio * 16 + hh * 8 + e;
        *(unsigned short*)(base + t * 256 + ((j * 2) ^ ((t & 7) << 4))) = val;
      }
    }
  };

  stage(0, 0);
  __syncthreads();
  int buf = 0;
  for (int it = 0; it < 4; ++it) {
    if (it < 3) stage(it + 1, buf ^ 1);
    f32x4 acc00 = {0,0,0,0}, acc01 = {0,0,0,0}, acc10 = {0,0,0,0}, acc11 = {0,0,0,0};
    const char* abase = (char*)as_ + ((buf * 2 + m_loc) * 32) * 256;
#pragma unroll
    for (int th = 0; th < 2; ++th) {
      const int t = th * 16 + l15;
#pragma unroll
      for (int ks = 0; ks < 4; ++ks) {
        const short8 av = *(const short8*)(abase + t * 256 +
                            ((ks * 64 + l4 * 16) ^ ((t & 7) << 4)));
        if (th == 0) {
          acc00 = __builtin_amdgcn_mfma_f32_16x16x32_bf16(av, bfr[0][ks], acc00, 0, 0, 0);
          acc10 = __builtin_amdgcn_mfma_f32_16x16x32_bf16(av, bfr[1][ks], acc10, 0, 0, 0);
        } else {
          acc01 = __builtin_amdgcn_mfma_f32_16x16x32_bf16(av, bfr[0][ks], acc01, 0, 0, 0);
          acc11 = __builtin_amdgcn_mfma_f32_16x16x32_bf16(av, bfr[1][ks], acc11, 0, 0, 0);
        }
      }
    }
    const size_t t0 = (size_t)(tok0 + strip * 128 + it * 32 + l4 * 4);
    float* y0 = y + (size_t)m * 64 + ah * 32 + l15;
#pragma unroll
    for (int jj = 0; jj < 4; ++jj) {
      y0[(t0 + jj) * DOUT]      = acc00[jj] + bv0;
      y0[(t0 + jj) * DOUT + 16] = acc10[jj] + bv1;
      y0[(t0 + 16 + jj) * DOUT]      = acc01[jj] + bv0;
      y0[(t0 + 16 + jj) * DOUT + 16] = acc11[jj] + bv1;
    }
    __syncthreads();
    buf ^= 1;
  }
}

extern "C" void kernel_launch(void* const* d_in, const int* in_sizes, int n_in,
                              void* d_out, int out_size, void* d_ws, size_t ws_size,
                              hipStream_t stream) {
  const float* x    = (const float*)d_in[0];
  const float* bl   = (const float*)d_in[1];
  const float* br   = (const float*)d_in[2];
  const float* bias = (const float*)d_in[3];
  float* y = (float*)d_out;

  unsigned short* rt   = (unsigned short*)d_ws;          // 1 MB
  unsigned short* ltw  = rt + 64 * 8192;                 // 1 MB
  unsigned short* hbuf = ltw + 64 * 8192;                // chunk*8192*2 B

  const size_t fixed = (size_t)2 * 64 * 8192 * 2;
  int chunk = 4096;                                      // h chunk L3-resident
  while (chunk > 256 && fixed + (size_t)chunk * 8192 * 2 > ws_size) chunk >>= 1;
  const int nchunk = NTOK / chunk;

  prep<<<128, 256, 0, stream>>>(br, bl, rt, ltw);
  for (int c = 0; c < nchunk; ++c) {
    k1<<<dim3(chunk / 256, 64), 256, 0, stream>>>(x, rt, hbuf, c * chunk);
    k2<<<dim3(chunk / 128, 32), 256, 0, stream>>>(hbuf, ltw, bias, y, c * chunk);
  }
}